// Round 1
// baseline (881.725 us; speedup 1.0000x reference)
//
#include <hip/hip_runtime.h>

// InverseConsistencyLoss on MI355X.
// Inputs: dvf_fwd, dvf_bwd: (B=2, 3, 128,128,128) fp32.
// out[0] = mean((F + warp(G,F))^2) + mean((G + warp(F,G))^2)
// Sample coordinate per axis reduces to clip(base_index + dvf, 0, 127)
// (align_corners=True round-trip cancels). Output voxel (d,h,w) samples
// V at (z=clip(w+a2), y=clip(h+a1), x=clip(d+a0)) with x the fastest dim.

#define CS   2097152          // 128^3 channel stride (floats)
#define BS   (3*CS)           // batch stride
#define NPOS (2*CS)           // total positions (B * 128^3)
#define NBLK 2048
#define NTHR 256
#define INV_N (1.0f/12582912.0f)   // 1 / (2*3*128^3)

__device__ __forceinline__ float tri(const float* __restrict__ v,
                                     int zy00, int zy01, int zy10, int zy11,
                                     int x0, int x1,
                                     float wz, float wy, float wx) {
    float c000 = v[zy00 + x0], c001 = v[zy00 + x1];
    float c010 = v[zy01 + x0], c011 = v[zy01 + x1];
    float c100 = v[zy10 + x0], c101 = v[zy10 + x1];
    float c110 = v[zy11 + x0], c111 = v[zy11 + x1];
    float c00 = c000 + wx * (c001 - c000);
    float c01 = c010 + wx * (c011 - c010);
    float c10 = c100 + wx * (c101 - c100);
    float c11 = c110 + wx * (c111 - c110);
    float c0  = c00  + wy * (c01  - c00);
    float c1  = c10  + wy * (c11  - c10);
    return c0 + wz * (c1 - c0);
}

// err^2 contribution of one direction at one voxel.
// a0,a1,a2: apply-field (and additive) values at (d,h,w); Vb: warped volume base (3ch).
__device__ __forceinline__ float dir_err2(const float* __restrict__ Vb,
                                          float a0, float a1, float a2,
                                          int d, int h, int w) {
    float fx = fminf(fmaxf((float)d + a0, 0.0f), 127.0f);
    float fy = fminf(fmaxf((float)h + a1, 0.0f), 127.0f);
    float fz = fminf(fmaxf((float)w + a2, 0.0f), 127.0f);
    int x0 = (int)fx, y0 = (int)fy, z0 = (int)fz;   // fx>=0 so trunc==floor
    float wx = fx - (float)x0, wy = fy - (float)y0, wz = fz - (float)z0;
    int x1 = min(x0 + 1, 127), y1 = min(y0 + 1, 127), z1 = min(z0 + 1, 127);
    int zy00 = ((z0 << 7) | y0) << 7;
    int zy01 = ((z0 << 7) | y1) << 7;
    int zy10 = ((z1 << 7) | y0) << 7;
    int zy11 = ((z1 << 7) | y1) << 7;
    float s0 = tri(Vb,        zy00, zy01, zy10, zy11, x0, x1, wz, wy, wx);
    float s1 = tri(Vb + CS,   zy00, zy01, zy10, zy11, x0, x1, wz, wy, wx);
    float s2 = tri(Vb + 2*CS, zy00, zy01, zy10, zy11, x0, x1, wz, wy, wx);
    float e0 = a0 + s0, e1 = a1 + s1, e2 = a2 + s2;
    return e0 * e0 + e1 * e1 + e2 * e2;
}

__global__ __launch_bounds__(NTHR)
void icl_partial(const float* __restrict__ F, const float* __restrict__ G,
                 float* __restrict__ partial) {
    float acc = 0.0f;
    int tid = blockIdx.x * NTHR + threadIdx.x;
    for (int p = tid; p < NPOS; p += NBLK * NTHR) {
        int b = p >> 21;
        int r = p & (CS - 1);
        int d = r >> 14, h = (r >> 7) & 127, w = r & 127;
        const float* Fb = F + b * BS;
        const float* Gb = G + b * BS;
        float a0 = Fb[r], a1 = Fb[CS + r], a2 = Fb[2*CS + r];
        float g0 = Gb[r], g1 = Gb[CS + r], g2 = Gb[2*CS + r];
        // fwd: coords+additive from F, sample G
        acc += dir_err2(Gb, a0, a1, a2, d, h, w);
        // bwd: coords+additive from G, sample F
        acc += dir_err2(Fb, g0, g1, g2, d, h, w);
    }
    // wave reduce (64 lanes)
    #pragma unroll
    for (int o = 32; o > 0; o >>= 1) acc += __shfl_down(acc, o);
    __shared__ float ws[NTHR / 64];
    if ((threadIdx.x & 63) == 0) ws[threadIdx.x >> 6] = acc;
    __syncthreads();
    if (threadIdx.x == 0) {
        float s = 0.0f;
        #pragma unroll
        for (int i = 0; i < NTHR / 64; ++i) s += ws[i];
        partial[blockIdx.x] = s;
    }
}

__global__ __launch_bounds__(NTHR)
void icl_final(const float* __restrict__ partial, float* __restrict__ out) {
    float a = 0.0f;
    for (int i = threadIdx.x; i < NBLK; i += NTHR) a += partial[i];
    #pragma unroll
    for (int o = 32; o > 0; o >>= 1) a += __shfl_down(a, o);
    __shared__ float ws[NTHR / 64];
    if ((threadIdx.x & 63) == 0) ws[threadIdx.x >> 6] = a;
    __syncthreads();
    if (threadIdx.x == 0) {
        float s = 0.0f;
        #pragma unroll
        for (int i = 0; i < NTHR / 64; ++i) s += ws[i];
        out[0] = s * INV_N;
    }
}

extern "C" void kernel_launch(void* const* d_in, const int* in_sizes, int n_in,
                              void* d_out, int out_size, void* d_ws, size_t ws_size,
                              hipStream_t stream) {
    const float* F = (const float*)d_in[0];   // dvf_fwd
    const float* G = (const float*)d_in[1];   // dvf_bwd
    float* partial = (float*)d_ws;            // NBLK floats of scratch
    icl_partial<<<NBLK, NTHR, 0, stream>>>(F, G, partial);
    icl_final<<<1, NTHR, 0, stream>>>(partial, (float*)d_out);
}

// Round 2
// 240.082 us; speedup vs baseline: 3.6726x; 3.6726x over previous
//
#include <hip/hip_runtime.h>

// InverseConsistencyLoss on MI355X — round 2: 3D-tiled, d-fastest lanes.
// Inputs: dvf_fwd, dvf_bwd: (B=2, 3, 128,128,128) fp32.
// out[0] = mean((F + warp(G,F))^2) + mean((G + warp(F,G))^2)
// Sample coordinate per axis reduces to clip(base + dvf, 0, 127); output voxel
// (d,h,w) samples V at (z=clip(w+a2), y=clip(h+a1), x=clip(d+a0)), x fastest.
// Each block: one direction, tile (64 d x 4 h x 16 w). Stage apply-field 3ch
// via LDS transpose (coalesced float4 along w), compute with lane==d so the
// gather's fastest coordinate is lane-contiguous (~3 lines/wave-gather in x).

#define CS   2097152          // 128^3 channel stride (floats)
#define BS   (3*CS)           // batch stride
#define NBLK 2048             // 2 dir * 2 b * 2 dt * 32 ht * 8 wt
#define NTHR 256
#define INV_N (1.0f/12582912.0f)   // 1 / (2*3*128^3)

__device__ __forceinline__ float tri(const float* __restrict__ v,
                                     int zy00, int zy01, int zy10, int zy11,
                                     int x0, int x1,
                                     float wz, float wy, float wx) {
    float c000 = v[zy00 + x0], c001 = v[zy00 + x1];
    float c010 = v[zy01 + x0], c011 = v[zy01 + x1];
    float c100 = v[zy10 + x0], c101 = v[zy10 + x1];
    float c110 = v[zy11 + x0], c111 = v[zy11 + x1];
    float c00 = c000 + wx * (c001 - c000);
    float c01 = c010 + wx * (c011 - c010);
    float c10 = c100 + wx * (c101 - c100);
    float c11 = c110 + wx * (c111 - c110);
    float c0  = c00  + wy * (c01  - c00);
    float c1  = c10  + wy * (c11  - c10);
    return c0 + wz * (c1 - c0);
}

__device__ __forceinline__ float dir_err2(const float* __restrict__ Vb,
                                          float a0, float a1, float a2,
                                          int d, int h, int w) {
    float fx = fminf(fmaxf((float)d + a0, 0.0f), 127.0f);
    float fy = fminf(fmaxf((float)h + a1, 0.0f), 127.0f);
    float fz = fminf(fmaxf((float)w + a2, 0.0f), 127.0f);
    int x0 = (int)fx, y0 = (int)fy, z0 = (int)fz;
    float wx = fx - (float)x0, wy = fy - (float)y0, wz = fz - (float)z0;
    int x1 = min(x0 + 1, 127), y1 = min(y0 + 1, 127), z1 = min(z0 + 1, 127);
    int zy00 = ((z0 << 7) | y0) << 7;
    int zy01 = ((z0 << 7) | y1) << 7;
    int zy10 = ((z1 << 7) | y0) << 7;
    int zy11 = ((z1 << 7) | y1) << 7;
    float s0 = tri(Vb,        zy00, zy01, zy10, zy11, x0, x1, wz, wy, wx);
    float s1 = tri(Vb + CS,   zy00, zy01, zy10, zy11, x0, x1, wz, wy, wx);
    float s2 = tri(Vb + 2*CS, zy00, zy01, zy10, zy11, x0, x1, wz, wy, wx);
    float e0 = a0 + s0, e1 = a1 + s1, e2 = a2 + s2;
    return e0 * e0 + e1 * e1 + e2 * e2;
}

__global__ __launch_bounds__(NTHR)
void icl_partial(const float* __restrict__ F, const float* __restrict__ G,
                 float* __restrict__ partial) {
    // LDS: apply field, layout [c][h(4)][w(16)][d(64)] = 12288 floats = 48 KB
    __shared__ float sA[12288];

    // XCD swizzle: 2048 blocks = 8 XCDs x 256; each XCD gets one contiguous
    // (dir,b,dt) slice (32 ht x 8 wt = 256 tiles) for L2 halo reuse.
    int orig = blockIdx.x;
    int id = ((orig & 7) << 8) | (orig >> 3);
    int wt  = id & 7;
    int ht  = (id >> 3) & 31;
    int dt  = (id >> 8) & 1;
    int b   = (id >> 9) & 1;
    int dir = id >> 10;

    const float* A = dir ? G : F;   // apply field (coords + additive)
    const float* V = dir ? F : G;   // sampled volume
    const float* Ab = A + b * BS;
    const float* Vb = V + b * BS;
    int d0 = dt << 6, h0 = ht << 2, w0 = wt << 4;

    // ---- stage: 3 ch x 64 d x 4 h x 16 w, coalesced float4 along w ----
    int t = threadIdx.x;
    #pragma unroll
    for (int j = 0; j < 12; ++j) {
        int L   = (j << 10) + (t << 2);   // linear float index, 12288 total
        int c   = L >> 12;
        int rem = L & 4095;
        int row = rem >> 4;               // 0..255 = d_l*4 + h_l
        int w_l = rem & 15;               // multiple of 4
        int d_l = row >> 2, h_l = row & 3;
        const float4 v = *(const float4*)(Ab + c * CS + ((d0 + d_l) << 14)
                                          + ((h0 + h_l) << 7) + w0 + w_l);
        int base = ((c * 4 + h_l) * 16 + w_l) * 64 + d_l;
        sA[base]       = v.x;
        sA[base + 64]  = v.y;
        sA[base + 128] = v.z;
        sA[base + 192] = v.w;
    }
    __syncthreads();

    // ---- compute: lane == d_l; wave wv owns h-row wv, iterates 16 w ----
    int lane = t & 63, wv = t >> 6;
    int d = d0 + lane;
    float acc = 0.0f;
    #pragma unroll 4
    for (int i = 0; i < 16; ++i) {
        int h = h0 + wv, w = w0 + i;
        int hwbase = (wv * 16 + i) * 64 + lane;
        float a0 = sA[hwbase];
        float a1 = sA[4096 + hwbase];
        float a2 = sA[8192 + hwbase];
        acc += dir_err2(Vb, a0, a1, a2, d, h, w);
    }

    // ---- block reduce ----
    #pragma unroll
    for (int o = 32; o > 0; o >>= 1) acc += __shfl_down(acc, o);
    __shared__ float ws[NTHR / 64];
    if ((t & 63) == 0) ws[t >> 6] = acc;
    __syncthreads();
    if (t == 0) {
        float s = 0.0f;
        #pragma unroll
        for (int i = 0; i < NTHR / 64; ++i) s += ws[i];
        partial[blockIdx.x] = s;
    }
}

__global__ __launch_bounds__(NTHR)
void icl_final(const float* __restrict__ partial, float* __restrict__ out) {
    float a = 0.0f;
    for (int i = threadIdx.x; i < NBLK; i += NTHR) a += partial[i];
    #pragma unroll
    for (int o = 32; o > 0; o >>= 1) a += __shfl_down(a, o);
    __shared__ float ws[NTHR / 64];
    if ((threadIdx.x & 63) == 0) ws[threadIdx.x >> 6] = a;
    __syncthreads();
    if (threadIdx.x == 0) {
        float s = 0.0f;
        #pragma unroll
        for (int i = 0; i < NTHR / 64; ++i) s += ws[i];
        out[0] = s * INV_N;
    }
}

extern "C" void kernel_launch(void* const* d_in, const int* in_sizes, int n_in,
                              void* d_out, int out_size, void* d_ws, size_t ws_size,
                              hipStream_t stream) {
    const float* F = (const float*)d_in[0];   // dvf_fwd
    const float* G = (const float*)d_in[1];   // dvf_bwd
    float* partial = (float*)d_ws;            // NBLK floats of scratch
    icl_partial<<<NBLK, NTHR, 0, stream>>>(F, G, partial);
    icl_final<<<1, NTHR, 0, stream>>>(partial, (float*)d_out);
}